// Round 18
// baseline (209.897 us; speedup 1.0000x reference)
//
#include <hip/hip_runtime.h>

// out = (B @ X) @ W — fused gather+GEMM against L3-RESIDENT bf16 X:
//   wtrans: Wt_bf16[n][k] = bf16(W[k][n])
//   hist/scan/fill: CSR build
//   cvt:    xb = bf16(X)  (102 MB — fits L3 together with out)
//   fused:  16-wave blocks; per iter, wave w gathers out-row it*16+w from xb
//           (8-deep independent 512B reads, fp32 accum), deposits bf16 into a
//           double-buffered 16-row LDS tile (XOR-swizzled); wave projects the
//           tile against its 16-col W-slice in 32 VGPRs (8 MFMA/iter);
//           one barrier/iter; next gather batch issued BEFORE the MFMAs.

typedef short bf16x8 __attribute__((ext_vector_type(8)));
typedef short short8 __attribute__((ext_vector_type(8)));
typedef float f32x4  __attribute__((ext_vector_type(4)));

#define FGRID 512

static __device__ __forceinline__ unsigned short f2bf(float f) {
    union { float f; unsigned u; } a; a.f = f;
    unsigned r = a.u + 0x7FFFu + ((a.u >> 16) & 1u);   // RNE
    return (unsigned short)(r >> 16);
}

static __device__ __forceinline__ float bf2f(unsigned short h) {
    union { unsigned u; float f; } a; a.u = (unsigned)h << 16;
    return a.f;
}

static __device__ __forceinline__ unsigned pack2(float f0, float f1) {
    return (unsigned)f2bf(f0) | ((unsigned)f2bf(f1) << 16);
}

__global__ __launch_bounds__(256) void wtrans_kernel(
    const float* __restrict__ W, unsigned short* __restrict__ Wt)
{
    int k = blockIdx.x;
    int n = threadIdx.x;
    Wt[(size_t)n * 256 + k] = f2bf(W[(size_t)k * 256 + n]);
}

__global__ __launch_bounds__(256) void hist_kernel(
    const int* __restrict__ b_rows, int* __restrict__ cnt, int nnz)
{
    int i = blockIdx.x * 256 + threadIdx.x;
    if (i < nnz) atomicAdd(&cnt[b_rows[i]], 1);
}

__global__ __launch_bounds__(1024) void scan_part_kernel(
    const int* __restrict__ cnt, int* __restrict__ partials, int M)
{
    int tid = threadIdx.x;
    int base = blockIdx.x * 4096;
    int s = 0;
    #pragma unroll
    for (int k = 0; k < 4; ++k) {
        int i = base + k * 1024 + tid;
        if (i < M) s += cnt[i];
    }
    #pragma unroll
    for (int d = 1; d < 64; d <<= 1) s += __shfl_xor(s, d);
    __shared__ int wsum[16];
    int lane = tid & 63, wid = tid >> 6;
    if (lane == 0) wsum[wid] = s;
    __syncthreads();
    if (tid == 0) {
        int t = 0;
        #pragma unroll
        for (int w = 0; w < 16; ++w) t += wsum[w];
        partials[blockIdx.x] = t;
    }
}

__global__ __launch_bounds__(64) void scan_mid_kernel(
    int* __restrict__ partials, int* __restrict__ off, int np, int M)
{
    int lane = threadIdx.x;
    int v = (lane < np) ? partials[lane] : 0;
    int x = v;
    #pragma unroll
    for (int d = 1; d < 64; d <<= 1) { int y = __shfl_up(x, d); if (lane >= d) x += y; }
    if (lane < np) partials[lane] = x - v;
    if (lane == 63) off[M] = x;
}

__global__ __launch_bounds__(1024) void scan_apply_kernel(
    const int* __restrict__ cnt, const int* __restrict__ partials,
    int* __restrict__ off, int* __restrict__ cursor, int M)
{
    int tid = threadIdx.x;
    int base = blockIdx.x * 4096 + tid * 4;
    int4 v = make_int4(0, 0, 0, 0);
    if (base + 3 < M) v = *reinterpret_cast<const int4*>(cnt + base);
    else {
        if (base + 0 < M) v.x = cnt[base + 0];
        if (base + 1 < M) v.y = cnt[base + 1];
        if (base + 2 < M) v.z = cnt[base + 2];
    }
    int s1 = v.x + v.y, s2 = s1 + v.z, tsum = s2 + v.w;
    int x = tsum;
    int lane = tid & 63, wid = tid >> 6;
    #pragma unroll
    for (int d = 1; d < 64; d <<= 1) { int y = __shfl_up(x, d); if (lane >= d) x += y; }
    __shared__ int wsum[16];
    if (lane == 63) wsum[wid] = x;
    __syncthreads();
    if (wid == 0 && lane < 16) {
        int w = wsum[lane];
        int xx = w;
        #pragma unroll
        for (int d = 1; d < 16; d <<= 1) { int y = __shfl_up(xx, d); if (lane >= d) xx += y; }
        wsum[lane] = xx - w;
    }
    __syncthreads();
    int excl = (x - tsum) + wsum[wid] + partials[blockIdx.x];
    int o0 = excl, o1 = excl + v.x, o2 = excl + s1, o3 = excl + s2;
    if (base + 0 < M) { off[base + 0] = o0; cursor[base + 0] = o0; }
    if (base + 1 < M) { off[base + 1] = o1; cursor[base + 1] = o1; }
    if (base + 2 < M) { off[base + 2] = o2; cursor[base + 2] = o2; }
    if (base + 3 < M) { off[base + 3] = o3; cursor[base + 3] = o3; }
}

__global__ __launch_bounds__(256) void fill_kernel(
    const float* __restrict__ b_vals, const int* __restrict__ b_rows,
    const int* __restrict__ b_cols, int* __restrict__ cursor,
    int* __restrict__ csr_col, float* __restrict__ csr_val, int nnz)
{
    int i = blockIdx.x * 256 + threadIdx.x;
    if (i < nnz) {
        int r = b_rows[i];
        int pos = atomicAdd(&cursor[r], 1);
        csr_col[pos] = b_cols[i];
        csr_val[pos] = b_vals[i];
    }
}

// xb = bf16(X), grid-stride, 8 elems/thread/iter. NT loads (X single-use).
__global__ __launch_bounds__(256) void cvt_kernel(
    const float* __restrict__ X, unsigned short* __restrict__ xb, int total8)
{
    int stride = gridDim.x * 256;
    for (int i = blockIdx.x * 256 + threadIdx.x; i < total8; i += stride) {
        const f32x4* p = reinterpret_cast<const f32x4*>(X + (size_t)i * 8);
        f32x4 a = __builtin_nontemporal_load(p);
        f32x4 b = __builtin_nontemporal_load(p + 1);
        union { short8 v; unsigned u[4]; } r;
        r.u[0] = pack2(a[0], a[1]); r.u[1] = pack2(a[2], a[3]);
        r.u[2] = pack2(b[0], b[1]); r.u[3] = pack2(b[2], b[3]);
        *reinterpret_cast<short8*>(xb + (size_t)i * 8) = r.v;
    }
}

// Gather one out-row's first edge batch from bf16 xb: issue loads only.
#define GATHER_LOAD(row)                                                      \
    gs = off[row]; ge = off[row + 1];                                         \
    gn = ge - gs; if (gn > 8) gn = 8;                                         \
    _Pragma("unroll")                                                         \
    for (int t = 0; t < 8; ++t)                                               \
        if (t < gn) { gc[t] = csr_col[gs + t]; gv[t] = csr_val[gs + t]; }     \
    _Pragma("unroll")                                                         \
    for (int t = 0; t < 8; ++t)                                               \
        if (t < gn) gx[t] = *reinterpret_cast<const ushort4*>(                \
            xb + (size_t)gc[t] * 256 + lane * 4);

#define GATHER_REDUCE()                                                       \
    _Pragma("unroll")                                                         \
    for (int t = 0; t < 8; ++t)                                               \
        if (t < gn) {                                                         \
            acc.x += gv[t] * bf2f(gx[t].x); acc.y += gv[t] * bf2f(gx[t].y);   \
            acc.z += gv[t] * bf2f(gx[t].z); acc.w += gv[t] * bf2f(gx[t].w);   \
        }

__global__ __launch_bounds__(1024, 2) void fused_kernel(
    const unsigned short* __restrict__ xb, const unsigned short* __restrict__ Wt,
    const float* __restrict__ csr_val, const int* __restrict__ csr_col,
    const int* __restrict__ off, float* __restrict__ out, int ntiles)
{
    __shared__ __align__(16) unsigned char tile[2][16 * 512];   // 16 KB

    int tid = threadIdx.x;
    int lane = tid & 63, w = tid >> 6;       // w: row-in-tile AND 16-col slice
    int arow = lane & 15, kg = lane >> 4;
    int xo_w = (w & 7) << 4;
    int xo_a = (arow & 7) << 4;

    // B-slice (cols [w*16, +16)) in registers: 8 frags = 32 VGPR
    bf16x8 breg[8];
    {
        const char* wt = reinterpret_cast<const char*>(Wt);
        size_t nb = (size_t)(w * 16 + arow) * 512 + kg * 16;
        #pragma unroll
        for (int s = 0; s < 8; ++s)
            breg[s] = *reinterpret_cast<const bf16x8*>(wt + nb + s * 64);
    }

    int gs, ge, gn;
    int gc[8]; float gv[8]; ushort4 gx[8];

    // ---- prologue: gather + deposit tile 0
    {
        int row = blockIdx.x * 16 + w;
        float4 acc = make_float4(0.f, 0.f, 0.f, 0.f);
        GATHER_LOAD(row);
        for (;;) {
            GATHER_REDUCE();
            gs += gn;
            if (gs >= ge) break;
            gn = ge - gs; if (gn > 8) gn = 8;
            #pragma unroll
            for (int t = 0; t < 8; ++t)
                if (t < gn) { gc[t] = csr_col[gs + t]; gv[t] = csr_val[gs + t]; }
            #pragma unroll
            for (int t = 0; t < 8; ++t)
                if (t < gn) gx[t] = *reinterpret_cast<const ushort4*>(
                    xb + (size_t)gc[t] * 256 + lane * 4);
        }
        ushort4 h;
        h.x = f2bf(acc.x); h.y = f2bf(acc.y); h.z = f2bf(acc.z); h.w = f2bf(acc.w);
        *reinterpret_cast<ushort4*>(tile[0] + w * 512 + ((lane * 8) ^ xo_w)) = h;
    }
    __syncthreads();

    for (int r = 0;; ++r) {
        int it  = blockIdx.x + r * FGRID;        // current tile (valid)
        int itn = it + FGRID;                    // next tile
        bool hasn = (itn < ntiles);
        int p = r & 1;

        // issue next row's first gather batch BEFORE compute (latency hides)
        if (hasn) { int row = itn * 16 + w; GATHER_LOAD(row); }

        // ---- compute current tile: A from LDS, B from registers
        f32x4 macc = {};
        #pragma unroll
        for (int s = 0; s < 8; ++s) {
            bf16x8 a = *reinterpret_cast<const bf16x8*>(
                tile[p] + arow * 512 + ((s * 64 + kg * 16) ^ xo_a));
            macc = __builtin_amdgcn_mfma_f32_16x16x32_bf16(a, breg[s], macc, 0, 0, 0);
        }
        int R = it * 16;
        #pragma unroll
        for (int rr = 0; rr < 4; ++rr)
            out[(size_t)(R + kg * 4 + rr) * 256 + w * 16 + arow] = macc[rr];

        if (!hasn) break;

        // ---- finish gather (reduce + rare extra batches), deposit tile[p^1]
        float4 acc = make_float4(0.f, 0.f, 0.f, 0.f);
        for (;;) {
            GATHER_REDUCE();
            gs += gn;
            if (gs >= ge) break;
            gn = ge - gs; if (gn > 8) gn = 8;
            #pragma unroll
            for (int t = 0; t < 8; ++t)
                if (t < gn) { gc[t] = csr_col[gs + t]; gv[t] = csr_val[gs + t]; }
            #pragma unroll
            for (int t = 0; t < 8; ++t)
                if (t < gn) gx[t] = *reinterpret_cast<const ushort4*>(
                    xb + (size_t)gc[t] * 256 + lane * 4);
        }
        ushort4 h;
        h.x = f2bf(acc.x); h.y = f2bf(acc.y); h.z = f2bf(acc.z); h.w = f2bf(acc.w);
        *reinterpret_cast<ushort4*>(tile[p ^ 1] + w * 512 + ((lane * 8) ^ xo_w)) = h;
        __syncthreads();
    }
}

extern "C" void kernel_launch(void* const* d_in, const int* in_sizes, int n_in,
                              void* d_out, int out_size, void* d_ws, size_t ws_size,
                              hipStream_t stream) {
    const float* x_src  = (const float*)d_in[0];
    const float* W      = (const float*)d_in[1];
    const float* b_vals = (const float*)d_in[2];
    const int*   b_rows = (const int*)d_in[3];
    const int*   b_cols = (const int*)d_in[4];

    const int C = 256;
    const int M = out_size / C;
    const int nnz = in_sizes[2];
    const int N = in_sizes[0] / C;

    char* ws = (char*)d_ws;
    unsigned short* Wt = (unsigned short*)ws;           ws += 256 * 256 * 2;
    int*   cnt     = (int*)ws;                          ws += (size_t)M * 4;
    int*   off     = (int*)ws;                          ws += (size_t)(M + 1) * 4;
    int*   cursor  = (int*)ws;                          ws += (size_t)M * 4;
    int*   partials= (int*)ws;                          ws += 64 * 4;
    int*   csr_col = (int*)ws;                          ws += (size_t)nnz * 4;
    float* csr_val = (float*)ws;                        ws += (size_t)nnz * 4;
    ws = (char*)(((size_t)ws + 63) & ~(size_t)63);
    unsigned short* xb = (unsigned short*)ws;           // N*512 bytes (~102 MB)

    float* out = (float*)d_out;

    hipMemsetAsync(cnt, 0, (size_t)M * 4, stream);

    wtrans_kernel<<<256, 256, 0, stream>>>(W, Wt);

    int nblk_nnz = (nnz + 255) / 256;
    hist_kernel<<<nblk_nnz, 256, 0, stream>>>(b_rows, cnt, nnz);

    int nb = (M + 4095) / 4096;
    scan_part_kernel<<<nb, 1024, 0, stream>>>(cnt, partials, M);
    scan_mid_kernel<<<1, 64, 0, stream>>>(partials, off, nb, M);
    scan_apply_kernel<<<nb, 1024, 0, stream>>>(cnt, partials, off, cursor, M);

    fill_kernel<<<nblk_nnz, 256, 0, stream>>>(b_vals, b_rows, b_cols, cursor,
                                              csr_col, csr_val, nnz);

    // convert LAST before fused so xb is maximally L3-resident
    cvt_kernel<<<2048, 256, 0, stream>>>(x_src, xb, N * C / 8);

    int ntiles = M / 16;                       // M=100000 -> 6250
    fused_kernel<<<FGRID, 1024, 0, stream>>>(xb, Wt, csr_val, csr_col, off,
                                             out, ntiles);
}